// Round 10
// baseline (255.465 us; speedup 1.0000x reference)
//
#include <hip/hip_runtime.h>
#include <hip/hip_bf16.h>

// ---------------------------------------------------------------------------
// 2-layer GCN:  x1 = relu(Agg(x @ W1) + b1);  out = relu(Agg(x1 @ W2) + b2)
// Agg: out[d] = dinv[d] * ( sum_{e: dst=d} hn[src_e] + hn[d] ),
//      hn[i] = (x@W)[i] * dinv[i]  (bf16),  dinv = rsqrt(deg+1).
// GEMM via v_mfma_f32_16x16x32_bf16; A tile in LDS, B-frags read DIRECTLY
// from the L2-resident 32KB wt image (no sW stage -> 17.4KB LDS, ~4 blk/CU).
// CSR: fixed-stride 512-node buckets, bucket-local LDS randomness only.
// Aggregate (round-7 config; converged ~62us): 16B/lane row gathers,
// 4 chains/16-lane group, csr prefetch.
// ---------------------------------------------------------------------------

#define F 128
#define BN 512
#define LOG_BN 9
#define MAXB 512
#define EPB 4096
#define CAP 10240          // edges per bucket region (fixed stride)
#define WSTRIDE 136        // padded u16 stride for LDS A-tile
#define WTS 128            // dense stride for the global wt image

typedef __attribute__((ext_vector_type(8))) short bh8;
typedef __attribute__((ext_vector_type(4))) float f32x4;

__device__ __forceinline__ unsigned short f2bf(float f) {
    __hip_bfloat16 h = __float2bfloat16(f);
    return *reinterpret_cast<unsigned short*>(&h);
}

__device__ __forceinline__ void acc8(float* a, uint4 q) {
    a[0] += __uint_as_float(q.x << 16);
    a[1] += __uint_as_float(q.x & 0xFFFF0000u);
    a[2] += __uint_as_float(q.y << 16);
    a[3] += __uint_as_float(q.y & 0xFFFF0000u);
    a[4] += __uint_as_float(q.z << 16);
    a[5] += __uint_as_float(q.z & 0xFFFF0000u);
    a[6] += __uint_as_float(q.w << 16);
    a[7] += __uint_as_float(q.w & 0xFFFF0000u);
}

// ----------------------------- CSR build ----------------------------------
__global__ __launch_bounds__(256) void bucket_scatter_kernel(
    const int* __restrict__ src, const int* __restrict__ dst, int E,
    int* __restrict__ gfill, unsigned int* __restrict__ pairs) {
    __shared__ int cnt[MAXB];
    __shared__ int base_l[MAXB];
    int t = threadIdx.x;
    for (int k = t; k < MAXB; k += 256) cnt[k] = 0;
    __syncthreads();
    int base = blockIdx.x * EPB;
    int d[16], r[16];
#pragma unroll
    for (int j = 0; j < 16; ++j) {
        int e = base + j * 256 + t;
        d[j] = -1; r[j] = 0;
        if (e < E) {
            d[j] = dst[e];
            r[j] = atomicAdd(&cnt[d[j] >> LOG_BN], 1);
        }
    }
    __syncthreads();
    for (int k = t; k < MAXB; k += 256)
        base_l[k] = cnt[k] ? atomicAdd(&gfill[k], cnt[k]) : 0;
    __syncthreads();
#pragma unroll
    for (int j = 0; j < 16; ++j) {
        int e = base + j * 256 + t;
        if (e < E) {
            int b = d[j] >> LOG_BN;
            int pos = base_l[b] + r[j];
            if (pos < CAP) {
                unsigned int w = (unsigned int)src[e] |
                                 ((unsigned int)(d[j] & (BN - 1)) << 20);
                pairs[(size_t)b * CAP + pos] = w;
            }
        }
    }
}

__global__ __launch_bounds__(512) void bucket_build_kernel(
    const unsigned int* __restrict__ pairs, const int* __restrict__ gfill,
    int N, int2* __restrict__ offs2, float* __restrict__ dinv,
    int* __restrict__ csr) {
    __shared__ unsigned int spair[CAP];
    __shared__ int deg[BN];
    __shared__ int fill[BN];
    __shared__ int sc[BN];
    int b = blockIdx.x, t = threadIdx.x;
    int node0 = b << LOG_BN;
    int nN = min(BN, N - node0);
    int lo = b * CAP;
    int cnt = min(gfill[b], CAP);
    deg[t] = 0; fill[t] = 0;
    for (int i = t; i < cnt; i += 512) spair[i] = pairs[(size_t)lo + i];
    __syncthreads();
    for (int i = t; i < cnt; i += 512)
        atomicAdd(&deg[(spair[i] >> 20) & (BN - 1)], 1);
    __syncthreads();
    int v = deg[t];
    sc[t] = v;
    __syncthreads();
    for (int off = 1; off < BN; off <<= 1) {
        int x = (t >= off) ? sc[t - off] : 0;
        __syncthreads();
        sc[t] += x;
        __syncthreads();
    }
    int ex = sc[t] - v;
    if (t < nN) {
        int beg = lo + ex;
        offs2[node0 + t] = make_int2(beg, beg + v);
        dinv[node0 + t] = rsqrtf((float)v + 1.0f);
    }
    __syncthreads();
    sc[t] = ex;
    __syncthreads();
    for (int i = t; i < cnt; i += 512) {
        unsigned int w = spair[i];
        int dl = (w >> 20) & (BN - 1);
        int rr = atomicAdd(&fill[dl], 1);
        csr[lo + sc[dl] + rr] = (int)(w & 0xFFFFFu);
    }
}

// ---------------- W1,W2 -> Wt bf16 dense [128][WTS] ------------------------
__global__ __launch_bounds__(256) void wt_prep_kernel(
    const float* __restrict__ W1, const float* __restrict__ W2,
    unsigned short* __restrict__ wt1, unsigned short* __restrict__ wt2) {
    int gid = blockIdx.x * 256 + threadIdx.x;   // 0..4095
    const float* W = (gid < 2048) ? W1 : W2;
    unsigned short* wt = (gid < 2048) ? wt1 : wt2;
    int g = gid & 2047;
    int n = g >> 4;
    int kc = (g & 15) * 8;
    unsigned short u[8];
#pragma unroll
    for (int j = 0; j < 8; ++j) u[j] = f2bf(W[(size_t)(kc + j) * F + n]);
    uint4 v;
    v.x = (unsigned)u[0] | ((unsigned)u[1] << 16);
    v.y = (unsigned)u[2] | ((unsigned)u[3] << 16);
    v.z = (unsigned)u[4] | ((unsigned)u[5] << 16);
    v.w = (unsigned)u[6] | ((unsigned)u[7] << 16);
    *(uint4*)&wt[(size_t)n * WTS + kc] = v;
}

// --------------------------- MFMA GEMM ------------------------------------
// 128 rows per block (2 row-tiles of 64); 4 waves. A tile staged in LDS;
// B fragments read directly from the L2-resident wt image.
template <bool A_BF16>
__global__ __launch_bounds__(256) void gemm_mfma_kernel(
    const void* __restrict__ Ain, const unsigned short* __restrict__ wt,
    const float* __restrict__ dinv, unsigned short* __restrict__ hn, int N) {
    __shared__ unsigned short sA[64 * WSTRIDE];
    int t = threadIdx.x;
    int wid = t >> 6, lane = t & 63;
    int lr = lane & 15, lk = lane >> 4;

#pragma unroll
    for (int rt = 0; rt < 2; ++rt) {
        int row0 = blockIdx.x * 128 + rt * 64;
        if (row0 >= N) break;               // block-uniform

        // ---- stage A tile (64 rows) ----
        if (A_BF16) {
            const unsigned short* A = (const unsigned short*)Ain;
#pragma unroll
            for (int j = 0; j < 4; ++j) {
                int i = j * 256 + t;
                int r = i >> 4, c8 = i & 15;
                int grow = row0 + r;
                uint4 v = make_uint4(0, 0, 0, 0);
                if (grow < N) v = *(const uint4*)(A + (size_t)grow * F + c8 * 8);
                *(uint4*)&sA[r * WSTRIDE + c8 * 8] = v;
            }
        } else {
            const float* A = (const float*)Ain;
#pragma unroll
            for (int j = 0; j < 8; ++j) {
                int i = j * 256 + t;
                int r = i >> 5, c4 = i & 31;
                int grow = row0 + r;
                float4 v = make_float4(0.f, 0.f, 0.f, 0.f);
                if (grow < N) v = *(const float4*)(A + (size_t)grow * F + c4 * 4);
                unsigned int p0 = (unsigned)f2bf(v.x) | ((unsigned)f2bf(v.y) << 16);
                unsigned int p1 = (unsigned)f2bf(v.z) | ((unsigned)f2bf(v.w) << 16);
                *(uint2*)&sA[r * WSTRIDE + c4 * 4] = make_uint2(p0, p1);
            }
        }
        __syncthreads();

        // ---- preload A frags; sA becomes reusable after next barrier ----
        bh8 af[4];
        const unsigned short* aP = &sA[(wid * 16 + lr) * WSTRIDE + lk * 8];
#pragma unroll
        for (int ks = 0; ks < 4; ++ks) af[ks] = *(const bh8*)(aP + ks * 32);
        __syncthreads();

        f32x4 acc[8];
#pragma unroll
        for (int c = 0; c < 8; ++c) acc[c] = (f32x4){0.f, 0.f, 0.f, 0.f};

        // ---- MFMA: B-frags straight from global (L2-resident wt) ----
        const unsigned short* bP = wt + (size_t)lr * WTS + lk * 8;
#pragma unroll
        for (int ct = 0; ct < 8; ++ct) {
            const unsigned short* bq = bP + (size_t)ct * 16 * WTS;
            bh8 b0 = *(const bh8*)(bq);
            bh8 b1 = *(const bh8*)(bq + 32);
            bh8 b2 = *(const bh8*)(bq + 64);
            bh8 b3 = *(const bh8*)(bq + 96);
            acc[ct] = __builtin_amdgcn_mfma_f32_16x16x32_bf16(af[0], b0, acc[ct], 0, 0, 0);
            acc[ct] = __builtin_amdgcn_mfma_f32_16x16x32_bf16(af[1], b1, acc[ct], 0, 0, 0);
            acc[ct] = __builtin_amdgcn_mfma_f32_16x16x32_bf16(af[2], b2, acc[ct], 0, 0, 0);
            acc[ct] = __builtin_amdgcn_mfma_f32_16x16x32_bf16(af[3], b3, acc[ct], 0, 0, 0);
        }

        // ---- epilogue: scale by dinv, bf16, repack via sA, coalesced store
        float dv[4];
        int rbase = wid * 16 + lk * 4;
#pragma unroll
        for (int j = 0; j < 4; ++j) {
            int grow = row0 + rbase + j;
            dv[j] = (grow < N) ? dinv[grow] : 0.f;
        }
#pragma unroll
        for (int ct = 0; ct < 8; ++ct) {
#pragma unroll
            for (int j = 0; j < 4; ++j)
                sA[(rbase + j) * WSTRIDE + ct * 16 + lr] = f2bf(acc[ct][j] * dv[j]);
        }
        __syncthreads();
#pragma unroll
        for (int j = 0; j < 4; ++j) {
            int i = j * 256 + t;
            int r = i >> 4, c8 = i & 15;
            int grow = row0 + r;
            if (grow < N)
                *(uint4*)(hn + (size_t)grow * F + c8 * 8) =
                    *(const uint4*)&sA[r * WSTRIDE + c8 * 8];
        }
        __syncthreads();
    }
}

// --------------------------- aggregation ----------------------------------
// 32 lanes per node: eo = lane>>4 (edge parity), cg = lane&15 (16B column
// group). Four gather chains in flight per 16-lane group; csr prefetched.
template <bool OUT_BF16>
__global__ __launch_bounds__(256) void aggregate_kernel(
    const unsigned short* __restrict__ hn, const int* __restrict__ csr,
    const int2* __restrict__ offs2, const float* __restrict__ dinv,
    const float* __restrict__ bias, void* __restrict__ outv, int N) {
    int node = blockIdx.x * 8 + (threadIdx.x >> 5);
    if (node >= N) return;
    int half = threadIdx.x & 31;
    int eo = half >> 4;
    int cg = half & 15;

    const uint4* hn4 = (const uint4*)hn;   // 16 uint4 per 256B row
    float a0[8], a1[8], a2[8], a3[8];
#pragma unroll
    for (int j = 0; j < 8; ++j) { a0[j] = 0.f; a1[j] = 0.f; a2[j] = 0.f; a3[j] = 0.f; }
    if (eo == 0) {                          // self-loop on parity-0 group
        uint4 q = hn4[(size_t)node * 16 + cg];
        acc8(a0, q);
    }

    int2 oo = offs2[node];
    int e0 = oo.x + eo;                     // group's edges: e0, e0+2, ...
    int d = oo.y - e0;
    int cnt = (d <= 0) ? 0 : ((d + 1) >> 1);

    int i0 = (0 < cnt) ? csr[e0]     : -1;
    int i1 = (1 < cnt) ? csr[e0 + 2] : -1;
    int i2 = (2 < cnt) ? csr[e0 + 4] : -1;
    int i3 = (3 < cnt) ? csr[e0 + 6] : -1;
    int k = 0;
    while (k < cnt) {
        uint4 q0 = make_uint4(0,0,0,0), q1 = q0, q2 = q0, q3 = q0;
        if (i0 >= 0) q0 = hn4[(size_t)i0 * 16 + cg];
        if (i1 >= 0) q1 = hn4[(size_t)i1 * 16 + cg];
        if (i2 >= 0) q2 = hn4[(size_t)i2 * 16 + cg];
        if (i3 >= 0) q3 = hn4[(size_t)i3 * 16 + cg];
        int kn = k + 4;
        i0 = (kn     < cnt) ? csr[e0 + 2 * kn]     : -1;   // prefetch next
        i1 = (kn + 1 < cnt) ? csr[e0 + 2 * kn + 2] : -1;
        i2 = (kn + 2 < cnt) ? csr[e0 + 2 * kn + 4] : -1;
        i3 = (kn + 3 < cnt) ? csr[e0 + 2 * kn + 6] : -1;
        acc8(a0, q0);
        acc8(a1, q1);
        acc8(a2, q2);
        acc8(a3, q3);
        k = kn;
    }

#pragma unroll
    for (int j = 0; j < 8; ++j) {
        a0[j] += a1[j];
        a2[j] += a3[j];
        a0[j] += a2[j];
        a0[j] += __shfl_xor(a0[j], 16, 32);
    }

    if (eo == 0) {
        float sc = dinv[node];
        float4 b0 = ((const float4*)bias)[cg * 2];
        float4 b1 = ((const float4*)bias)[cg * 2 + 1];
        float o[8];
        o[0] = fmaxf(fmaf(a0[0], sc, b0.x), 0.f);
        o[1] = fmaxf(fmaf(a0[1], sc, b0.y), 0.f);
        o[2] = fmaxf(fmaf(a0[2], sc, b0.z), 0.f);
        o[3] = fmaxf(fmaf(a0[3], sc, b0.w), 0.f);
        o[4] = fmaxf(fmaf(a0[4], sc, b1.x), 0.f);
        o[5] = fmaxf(fmaf(a0[5], sc, b1.y), 0.f);
        o[6] = fmaxf(fmaf(a0[6], sc, b1.z), 0.f);
        o[7] = fmaxf(fmaf(a0[7], sc, b1.w), 0.f);
        if (OUT_BF16) {
            uint4 p;
            p.x = (unsigned)f2bf(o[0]) | ((unsigned)f2bf(o[1]) << 16);
            p.y = (unsigned)f2bf(o[2]) | ((unsigned)f2bf(o[3]) << 16);
            p.z = (unsigned)f2bf(o[4]) | ((unsigned)f2bf(o[5]) << 16);
            p.w = (unsigned)f2bf(o[6]) | ((unsigned)f2bf(o[7]) << 16);
            ((uint4*)outv)[(size_t)node * 16 + cg] = p;
        } else {
            float4* op = (float4*)((float*)outv + (size_t)node * F + cg * 8);
            op[0] = make_float4(o[0], o[1], o[2], o[3]);
            op[1] = make_float4(o[4], o[5], o[6], o[7]);
        }
    }
}

extern "C" void kernel_launch(void* const* d_in, const int* in_sizes, int n_in,
                              void* d_out, int out_size, void* d_ws, size_t ws_size,
                              hipStream_t stream) {
    const float* x   = (const float*)d_in[0];
    const int*   ei  = (const int*)d_in[1];   // int64 in reference -> int32 here
    const float* W1  = (const float*)d_in[2];
    const float* b1  = (const float*)d_in[3];
    const float* W2  = (const float*)d_in[4];
    const float* b2  = (const float*)d_in[5];
    float* out       = (float*)d_out;

    int N = in_sizes[0] / F;
    int E = in_sizes[1] / 2;
    const int* esrc = ei;
    const int* edst = ei + E;

    int nbkt = (N + BN - 1) / BN;

    char* w = (char*)d_ws;
    auto alloc = [&](size_t bytes) {
        char* p = w;
        w += (bytes + 255) & ~(size_t)255;
        return p;
    };
    int*   gfill   = (int*)alloc((size_t)MAXB * 4);
    int2*  offs2   = (int2*)alloc((size_t)N * 8);
    float* dinv    = (float*)alloc((size_t)N * 4);
    unsigned int* pairs = (unsigned int*)alloc((size_t)nbkt * CAP * 4);
    int*   csr     = (int*)alloc((size_t)nbkt * CAP * 4);
    unsigned short* hn  = (unsigned short*)alloc((size_t)N * F * 2);
    unsigned short* wt1 = (unsigned short*)alloc((size_t)F * WTS * 2);
    unsigned short* wt2 = (unsigned short*)alloc((size_t)F * WTS * 2);
    // layer-1 bf16 activations live in spare d_out space (51.2MB f32 buffer,
    // x1b needs 25.6MB; layer-2 aggregate fully overwrites d_out afterwards)
    unsigned short* x1b = (unsigned short*)d_out;

    hipMemsetAsync(gfill, 0, (size_t)MAXB * 4, stream);

    int nbe = (E + EPB - 1) / EPB;
    bucket_scatter_kernel<<<nbe, 256, 0, stream>>>(esrc, edst, E, gfill, pairs);
    bucket_build_kernel<<<nbkt, 512, 0, stream>>>(pairs, gfill, N, offs2, dinv, csr);
    wt_prep_kernel<<<16, 256, 0, stream>>>(W1, W2, wt1, wt2);

    int gblocks = (N + 127) / 128;
    int ablocks = (N + 7) / 8;

    // layer 1
    gemm_mfma_kernel<false><<<gblocks, 256, 0, stream>>>(x, wt1, dinv, hn, N);
    aggregate_kernel<true><<<ablocks, 256, 0, stream>>>(hn, csr, offs2, dinv, b1, x1b, N);
    // layer 2
    gemm_mfma_kernel<true><<<gblocks, 256, 0, stream>>>(x1b, wt2, dinv, hn, N);
    aggregate_kernel<false><<<ablocks, 256, 0, stream>>>(hn, csr, offs2, dinv, b2, out, N);
}

// Round 11
// 224.613 us; speedup vs baseline: 1.1374x; 1.1374x over previous
//
#include <hip/hip_runtime.h>
#include <hip/hip_bf16.h>

// ---------------------------------------------------------------------------
// 2-layer GCN:  x1 = relu(Agg(x @ W1) + b1);  out = relu(Agg(x1 @ W2) + b2)
// Agg: out[d] = dinv[d] * ( sum_{e: dst=d} hn[src_e] + hn[d] ),
//      hn[i] = (x@W)[i] * dinv[i]  (bf16),  dinv = rsqrt(deg+1).
// GEMM via v_mfma_f32_16x16x32_bf16, W pre-transposed bf16, sW staged in LDS
// (r7 structure — proven). agg1+gemm2 FUSED: block aggregates 64 nodes
// directly into the LDS A-tile (sW staged before the agg phase so its
// latency hides), then runs the MFMA tile. Saves the 51MB x1 round-trip.
// Buffers: gemm1 -> hn in d_out; fused: d_out -> hn2 in ws; agg2: hn2 -> d_out.
// CSR: fixed-stride 512-node buckets, bucket-local LDS randomness only.
// ---------------------------------------------------------------------------

#define F 128
#define BN 512
#define LOG_BN 9
#define MAXB 512
#define EPB 4096
#define CAP 10240          // edges per bucket region (fixed stride)
#define WSTRIDE 136        // padded u16 stride (2-way max LDS bank aliasing)

typedef __attribute__((ext_vector_type(8))) short bh8;
typedef __attribute__((ext_vector_type(4))) float f32x4;

__device__ __forceinline__ unsigned short f2bf(float f) {
    __hip_bfloat16 h = __float2bfloat16(f);
    return *reinterpret_cast<unsigned short*>(&h);
}

__device__ __forceinline__ void acc8(float* a, uint4 q) {
    a[0] += __uint_as_float(q.x << 16);
    a[1] += __uint_as_float(q.x & 0xFFFF0000u);
    a[2] += __uint_as_float(q.y << 16);
    a[3] += __uint_as_float(q.y & 0xFFFF0000u);
    a[4] += __uint_as_float(q.z << 16);
    a[5] += __uint_as_float(q.z & 0xFFFF0000u);
    a[6] += __uint_as_float(q.w << 16);
    a[7] += __uint_as_float(q.w & 0xFFFF0000u);
}

// ----------------------------- CSR build ----------------------------------
__global__ __launch_bounds__(256) void bucket_scatter_kernel(
    const int* __restrict__ src, const int* __restrict__ dst, int E,
    int* __restrict__ gfill, unsigned int* __restrict__ pairs) {
    __shared__ int cnt[MAXB];
    __shared__ int base_l[MAXB];
    int t = threadIdx.x;
    for (int k = t; k < MAXB; k += 256) cnt[k] = 0;
    __syncthreads();
    int base = blockIdx.x * EPB;
    int d[16], r[16];
#pragma unroll
    for (int j = 0; j < 16; ++j) {
        int e = base + j * 256 + t;
        d[j] = -1; r[j] = 0;
        if (e < E) {
            d[j] = dst[e];
            r[j] = atomicAdd(&cnt[d[j] >> LOG_BN], 1);
        }
    }
    __syncthreads();
    for (int k = t; k < MAXB; k += 256)
        base_l[k] = cnt[k] ? atomicAdd(&gfill[k], cnt[k]) : 0;
    __syncthreads();
#pragma unroll
    for (int j = 0; j < 16; ++j) {
        int e = base + j * 256 + t;
        if (e < E) {
            int b = d[j] >> LOG_BN;
            int pos = base_l[b] + r[j];
            if (pos < CAP) {
                unsigned int w = (unsigned int)src[e] |
                                 ((unsigned int)(d[j] & (BN - 1)) << 20);
                pairs[(size_t)b * CAP + pos] = w;
            }
        }
    }
}

__global__ __launch_bounds__(512) void bucket_build_kernel(
    const unsigned int* __restrict__ pairs, const int* __restrict__ gfill,
    int N, int2* __restrict__ offs2, float* __restrict__ dinv,
    int* __restrict__ csr) {
    __shared__ unsigned int spair[CAP];
    __shared__ int deg[BN];
    __shared__ int fill[BN];
    __shared__ int sc[BN];
    int b = blockIdx.x, t = threadIdx.x;
    int node0 = b << LOG_BN;
    int nN = min(BN, N - node0);
    int lo = b * CAP;
    int cnt = min(gfill[b], CAP);
    deg[t] = 0; fill[t] = 0;
    for (int i = t; i < cnt; i += 512) spair[i] = pairs[(size_t)lo + i];
    __syncthreads();
    for (int i = t; i < cnt; i += 512)
        atomicAdd(&deg[(spair[i] >> 20) & (BN - 1)], 1);
    __syncthreads();
    int v = deg[t];
    sc[t] = v;
    __syncthreads();
    for (int off = 1; off < BN; off <<= 1) {
        int x = (t >= off) ? sc[t - off] : 0;
        __syncthreads();
        sc[t] += x;
        __syncthreads();
    }
    int ex = sc[t] - v;
    if (t < nN) {
        int beg = lo + ex;
        offs2[node0 + t] = make_int2(beg, beg + v);
        dinv[node0 + t] = rsqrtf((float)v + 1.0f);
    }
    __syncthreads();
    sc[t] = ex;
    __syncthreads();
    for (int i = t; i < cnt; i += 512) {
        unsigned int w = spair[i];
        int dl = (w >> 20) & (BN - 1);
        int rr = atomicAdd(&fill[dl], 1);
        csr[lo + sc[dl] + rr] = (int)(w & 0xFFFFFu);
    }
}

// ---------------- W1,W2 -> Wt bf16 padded [128][WSTRIDE] -------------------
__global__ __launch_bounds__(256) void wt_prep_kernel(
    const float* __restrict__ W1, const float* __restrict__ W2,
    unsigned short* __restrict__ wt1, unsigned short* __restrict__ wt2) {
    int gid = blockIdx.x * 256 + threadIdx.x;   // 0..4095
    const float* W = (gid < 2048) ? W1 : W2;
    unsigned short* wt = (gid < 2048) ? wt1 : wt2;
    int g = gid & 2047;
    int n = g >> 4;
    int kc = (g & 15) * 8;
    unsigned short u[8];
#pragma unroll
    for (int j = 0; j < 8; ++j) u[j] = f2bf(W[(size_t)(kc + j) * F + n]);
    uint4 v;
    v.x = (unsigned)u[0] | ((unsigned)u[1] << 16);
    v.y = (unsigned)u[2] | ((unsigned)u[3] << 16);
    v.z = (unsigned)u[4] | ((unsigned)u[5] << 16);
    v.w = (unsigned)u[6] | ((unsigned)u[7] << 16);
    *(uint4*)&wt[(size_t)n * WSTRIDE + kc] = v;
}

// --------------------------- MFMA GEMM (layer 1) ---------------------------
// 128 rows per block (2 row-tiles of 64; W staged once); 4 waves. r7-proven.
__global__ __launch_bounds__(256) void gemm_mfma_kernel(
    const float* __restrict__ A, const unsigned short* __restrict__ wt,
    const float* __restrict__ dinv, unsigned short* __restrict__ hn, int N) {
    __shared__ unsigned short sA[64 * WSTRIDE];
    __shared__ unsigned short sW[128 * WSTRIDE];
    int t = threadIdx.x;

    {   // stage Wt once per block (linear uint4 image copy)
        const uint4* ws = (const uint4*)wt;
        uint4* wd = (uint4*)sW;
#pragma unroll
        for (int j = 0; j < 9; ++j) {
            int i = j * 256 + t;
            if (i < 128 * WSTRIDE / 8) wd[i] = ws[i];
        }
    }

    int wid = t >> 6, lane = t & 63;
    int lr = lane & 15, lk = lane >> 4;

#pragma unroll
    for (int rt = 0; rt < 2; ++rt) {
        int row0 = blockIdx.x * 128 + rt * 64;
        if (row0 >= N) break;               // block-uniform

#pragma unroll
        for (int j = 0; j < 8; ++j) {
            int i = j * 256 + t;
            int r = i >> 5, c4 = i & 31;
            int grow = row0 + r;
            float4 v = make_float4(0.f, 0.f, 0.f, 0.f);
            if (grow < N) v = *(const float4*)(A + (size_t)grow * F + c4 * 4);
            unsigned int p0 = (unsigned)f2bf(v.x) | ((unsigned)f2bf(v.y) << 16);
            unsigned int p1 = (unsigned)f2bf(v.z) | ((unsigned)f2bf(v.w) << 16);
            *(uint2*)&sA[r * WSTRIDE + c4 * 4] = make_uint2(p0, p1);
        }
        __syncthreads();

        bh8 af[4];
        const unsigned short* aP = &sA[(wid * 16 + lr) * WSTRIDE + lk * 8];
#pragma unroll
        for (int ks = 0; ks < 4; ++ks) af[ks] = *(const bh8*)(aP + ks * 32);

        f32x4 acc[8];
#pragma unroll
        for (int c = 0; c < 8; ++c) acc[c] = (f32x4){0.f, 0.f, 0.f, 0.f};

        const unsigned short* bP = &sW[lr * WSTRIDE + lk * 8];
#pragma unroll
        for (int ct = 0; ct < 8; ++ct) {
            const unsigned short* bq = bP + ct * 16 * WSTRIDE;
            bh8 b0 = *(const bh8*)(bq);
            bh8 b1 = *(const bh8*)(bq + 32);
            bh8 b2 = *(const bh8*)(bq + 64);
            bh8 b3 = *(const bh8*)(bq + 96);
            acc[ct] = __builtin_amdgcn_mfma_f32_16x16x32_bf16(af[0], b0, acc[ct], 0, 0, 0);
            acc[ct] = __builtin_amdgcn_mfma_f32_16x16x32_bf16(af[1], b1, acc[ct], 0, 0, 0);
            acc[ct] = __builtin_amdgcn_mfma_f32_16x16x32_bf16(af[2], b2, acc[ct], 0, 0, 0);
            acc[ct] = __builtin_amdgcn_mfma_f32_16x16x32_bf16(af[3], b3, acc[ct], 0, 0, 0);
        }
        __syncthreads();

        float dv[4];
        int rbase = wid * 16 + lk * 4;
#pragma unroll
        for (int j = 0; j < 4; ++j) {
            int grow = row0 + rbase + j;
            dv[j] = (grow < N) ? dinv[grow] : 0.f;
        }
#pragma unroll
        for (int ct = 0; ct < 8; ++ct) {
#pragma unroll
            for (int j = 0; j < 4; ++j)
                sA[(rbase + j) * WSTRIDE + ct * 16 + lr] = f2bf(acc[ct][j] * dv[j]);
        }
        __syncthreads();
#pragma unroll
        for (int j = 0; j < 4; ++j) {
            int i = j * 256 + t;
            int r = i >> 4, c8 = i & 15;
            int grow = row0 + r;
            if (grow < N)
                *(uint4*)(hn + (size_t)grow * F + c8 * 8) =
                    *(const uint4*)&sA[r * WSTRIDE + c8 * 8];
        }
        __syncthreads();
    }
}

// -------------------- FUSED agg(layer1) + gemm(layer2) ---------------------
// Block = 256 threads, 64 nodes. Phase 0: issue sW stage (latency hides under
// agg). Phase 1: 8 half-waves aggregate 8 nodes each (r7 agg inner loop),
// relu+bias+dinv result written as bf16 straight into the LDS A-tile.
// Phase 2: 4 waves run the 64x128 MFMA tile, scale by dinv, store hn2.
__global__ __launch_bounds__(256) void fused_agg_gemm_kernel(
    const unsigned short* __restrict__ hn, const int* __restrict__ csr,
    const int2* __restrict__ offs2, const float* __restrict__ dinv,
    const float* __restrict__ bias, const unsigned short* __restrict__ wt,
    unsigned short* __restrict__ hn2, int N) {
    __shared__ unsigned short sA[64 * WSTRIDE];
    __shared__ unsigned short sW[128 * WSTRIDE];
    int t = threadIdx.x;
    int node0 = blockIdx.x * 64;

    {   // stage Wt (consumed after the agg-phase barrier)
        const uint4* ws = (const uint4*)wt;
        uint4* wd = (uint4*)sW;
#pragma unroll
        for (int j = 0; j < 9; ++j) {
            int i = j * 256 + t;
            if (i < 128 * WSTRIDE / 8) wd[i] = ws[i];
        }
    }

    int half = t & 31;
    int eo = half >> 4;
    int cg = half & 15;
    int hw = t >> 5;                        // half-wave id 0..7
    const uint4* hn4 = (const uint4*)hn;

    float4 bb0 = ((const float4*)bias)[cg * 2];
    float4 bb1 = ((const float4*)bias)[cg * 2 + 1];

    for (int it = 0; it < 8; ++it) {
        int node = node0 + hw * 8 + it;
        if (node >= N) break;               // half-wave-uniform

        float a0[8], a1[8], a2[8], a3[8];
#pragma unroll
        for (int j = 0; j < 8; ++j) { a0[j] = 0.f; a1[j] = 0.f; a2[j] = 0.f; a3[j] = 0.f; }
        if (eo == 0) {                      // self-loop on parity-0 group
            uint4 q = hn4[(size_t)node * 16 + cg];
            acc8(a0, q);
        }

        int2 oo = offs2[node];
        int e0 = oo.x + eo;
        int d = oo.y - e0;
        int cnt = (d <= 0) ? 0 : ((d + 1) >> 1);

        int i0 = (0 < cnt) ? csr[e0]     : -1;
        int i1 = (1 < cnt) ? csr[e0 + 2] : -1;
        int i2 = (2 < cnt) ? csr[e0 + 4] : -1;
        int i3 = (3 < cnt) ? csr[e0 + 6] : -1;
        int k = 0;
        while (k < cnt) {
            uint4 q0 = make_uint4(0,0,0,0), q1 = q0, q2 = q0, q3 = q0;
            if (i0 >= 0) q0 = hn4[(size_t)i0 * 16 + cg];
            if (i1 >= 0) q1 = hn4[(size_t)i1 * 16 + cg];
            if (i2 >= 0) q2 = hn4[(size_t)i2 * 16 + cg];
            if (i3 >= 0) q3 = hn4[(size_t)i3 * 16 + cg];
            int kn = k + 4;
            i0 = (kn     < cnt) ? csr[e0 + 2 * kn]     : -1;
            i1 = (kn + 1 < cnt) ? csr[e0 + 2 * kn + 2] : -1;
            i2 = (kn + 2 < cnt) ? csr[e0 + 2 * kn + 4] : -1;
            i3 = (kn + 3 < cnt) ? csr[e0 + 2 * kn + 6] : -1;
            acc8(a0, q0);
            acc8(a1, q1);
            acc8(a2, q2);
            acc8(a3, q3);
            k = kn;
        }

#pragma unroll
        for (int j = 0; j < 8; ++j) {
            a0[j] += a1[j];
            a2[j] += a3[j];
            a0[j] += a2[j];
            a0[j] += __shfl_xor(a0[j], 16, 32);
        }

        if (eo == 0) {                      // relu(x1) -> bf16 -> LDS A-tile
            float sc = dinv[node];
            float o[8];
            o[0] = fmaxf(fmaf(a0[0], sc, bb0.x), 0.f);
            o[1] = fmaxf(fmaf(a0[1], sc, bb0.y), 0.f);
            o[2] = fmaxf(fmaf(a0[2], sc, bb0.z), 0.f);
            o[3] = fmaxf(fmaf(a0[3], sc, bb0.w), 0.f);
            o[4] = fmaxf(fmaf(a0[4], sc, bb1.x), 0.f);
            o[5] = fmaxf(fmaf(a0[5], sc, bb1.y), 0.f);
            o[6] = fmaxf(fmaf(a0[6], sc, bb1.z), 0.f);
            o[7] = fmaxf(fmaf(a0[7], sc, bb1.w), 0.f);
            uint4 p;
            p.x = (unsigned)f2bf(o[0]) | ((unsigned)f2bf(o[1]) << 16);
            p.y = (unsigned)f2bf(o[2]) | ((unsigned)f2bf(o[3]) << 16);
            p.z = (unsigned)f2bf(o[4]) | ((unsigned)f2bf(o[5]) << 16);
            p.w = (unsigned)f2bf(o[6]) | ((unsigned)f2bf(o[7]) << 16);
            *(uint4*)&sA[(hw * 8 + it) * WSTRIDE + cg * 8] = p;
        }
    }
    __syncthreads();                        // A-tile + sW ready

    // ---- GEMM phase: 4 waves x 16 rows, K=128, 128 out-cols ----
    int wid = t >> 6, lane = t & 63;
    int lr = lane & 15, lk = lane >> 4;

    bh8 af[4];
    const unsigned short* aP = &sA[(wid * 16 + lr) * WSTRIDE + lk * 8];
#pragma unroll
    for (int ks = 0; ks < 4; ++ks) af[ks] = *(const bh8*)(aP + ks * 32);

    f32x4 acc[8];
#pragma unroll
    for (int c = 0; c < 8; ++c) acc[c] = (f32x4){0.f, 0.f, 0.f, 0.f};

    const unsigned short* bP = &sW[lr * WSTRIDE + lk * 8];
#pragma unroll
    for (int ct = 0; ct < 8; ++ct) {
        const unsigned short* bq = bP + ct * 16 * WSTRIDE;
        bh8 b0 = *(const bh8*)(bq);
        bh8 b1 = *(const bh8*)(bq + 32);
        bh8 b2 = *(const bh8*)(bq + 64);
        bh8 b3 = *(const bh8*)(bq + 96);
        acc[ct] = __builtin_amdgcn_mfma_f32_16x16x32_bf16(af[0], b0, acc[ct], 0, 0, 0);
        acc[ct] = __builtin_amdgcn_mfma_f32_16x16x32_bf16(af[1], b1, acc[ct], 0, 0, 0);
        acc[ct] = __builtin_amdgcn_mfma_f32_16x16x32_bf16(af[2], b2, acc[ct], 0, 0, 0);
        acc[ct] = __builtin_amdgcn_mfma_f32_16x16x32_bf16(af[3], b3, acc[ct], 0, 0, 0);
    }
    __syncthreads();

    float dv[4];
    int rbase = wid * 16 + lk * 4;
#pragma unroll
    for (int j = 0; j < 4; ++j) {
        int grow = node0 + rbase + j;
        dv[j] = (grow < N) ? dinv[grow] : 0.f;
    }
#pragma unroll
    for (int ct = 0; ct < 8; ++ct) {
#pragma unroll
        for (int j = 0; j < 4; ++j)
            sA[(rbase + j) * WSTRIDE + ct * 16 + lr] = f2bf(acc[ct][j] * dv[j]);
    }
    __syncthreads();
#pragma unroll
    for (int j = 0; j < 4; ++j) {
        int i = j * 256 + t;
        int r = i >> 4, c8 = i & 15;
        int grow = node0 + r;
        if (grow < N)
            *(uint4*)(hn2 + (size_t)grow * F + c8 * 8) =
                *(const uint4*)&sA[r * WSTRIDE + c8 * 8];
    }
}

// --------------------- aggregation (layer 2, fp32 out) ---------------------
__global__ __launch_bounds__(256) void aggregate_kernel(
    const unsigned short* __restrict__ hn, const int* __restrict__ csr,
    const int2* __restrict__ offs2, const float* __restrict__ dinv,
    const float* __restrict__ bias, float* __restrict__ outv, int N) {
    int node = blockIdx.x * 8 + (threadIdx.x >> 5);
    if (node >= N) return;
    int half = threadIdx.x & 31;
    int eo = half >> 4;
    int cg = half & 15;

    const uint4* hn4 = (const uint4*)hn;
    float a0[8], a1[8], a2[8], a3[8];
#pragma unroll
    for (int j = 0; j < 8; ++j) { a0[j] = 0.f; a1[j] = 0.f; a2[j] = 0.f; a3[j] = 0.f; }
    if (eo == 0) {
        uint4 q = hn4[(size_t)node * 16 + cg];
        acc8(a0, q);
    }

    int2 oo = offs2[node];
    int e0 = oo.x + eo;
    int d = oo.y - e0;
    int cnt = (d <= 0) ? 0 : ((d + 1) >> 1);

    int i0 = (0 < cnt) ? csr[e0]     : -1;
    int i1 = (1 < cnt) ? csr[e0 + 2] : -1;
    int i2 = (2 < cnt) ? csr[e0 + 4] : -1;
    int i3 = (3 < cnt) ? csr[e0 + 6] : -1;
    int k = 0;
    while (k < cnt) {
        uint4 q0 = make_uint4(0,0,0,0), q1 = q0, q2 = q0, q3 = q0;
        if (i0 >= 0) q0 = hn4[(size_t)i0 * 16 + cg];
        if (i1 >= 0) q1 = hn4[(size_t)i1 * 16 + cg];
        if (i2 >= 0) q2 = hn4[(size_t)i2 * 16 + cg];
        if (i3 >= 0) q3 = hn4[(size_t)i3 * 16 + cg];
        int kn = k + 4;
        i0 = (kn     < cnt) ? csr[e0 + 2 * kn]     : -1;
        i1 = (kn + 1 < cnt) ? csr[e0 + 2 * kn + 2] : -1;
        i2 = (kn + 2 < cnt) ? csr[e0 + 2 * kn + 4] : -1;
        i3 = (kn + 3 < cnt) ? csr[e0 + 2 * kn + 6] : -1;
        acc8(a0, q0);
        acc8(a1, q1);
        acc8(a2, q2);
        acc8(a3, q3);
        k = kn;
    }

#pragma unroll
    for (int j = 0; j < 8; ++j) {
        a0[j] += a1[j];
        a2[j] += a3[j];
        a0[j] += a2[j];
        a0[j] += __shfl_xor(a0[j], 16, 32);
    }

    if (eo == 0) {
        float sc = dinv[node];
        float4 b0 = ((const float4*)bias)[cg * 2];
        float4 b1 = ((const float4*)bias)[cg * 2 + 1];
        float o[8];
        o[0] = fmaxf(fmaf(a0[0], sc, b0.x), 0.f);
        o[1] = fmaxf(fmaf(a0[1], sc, b0.y), 0.f);
        o[2] = fmaxf(fmaf(a0[2], sc, b0.z), 0.f);
        o[3] = fmaxf(fmaf(a0[3], sc, b0.w), 0.f);
        o[4] = fmaxf(fmaf(a0[4], sc, b1.x), 0.f);
        o[5] = fmaxf(fmaf(a0[5], sc, b1.y), 0.f);
        o[6] = fmaxf(fmaf(a0[6], sc, b1.z), 0.f);
        o[7] = fmaxf(fmaf(a0[7], sc, b1.w), 0.f);
        float4* op = (float4*)(outv + (size_t)node * F + cg * 8);
        op[0] = make_float4(o[0], o[1], o[2], o[3]);
        op[1] = make_float4(o[4], o[5], o[6], o[7]);
    }
}

extern "C" void kernel_launch(void* const* d_in, const int* in_sizes, int n_in,
                              void* d_out, int out_size, void* d_ws, size_t ws_size,
                              hipStream_t stream) {
    const float* x   = (const float*)d_in[0];
    const int*   ei  = (const int*)d_in[1];   // int64 in reference -> int32 here
    const float* W1  = (const float*)d_in[2];
    const float* b1  = (const float*)d_in[3];
    const float* W2  = (const float*)d_in[4];
    const float* b2  = (const float*)d_in[5];
    float* out       = (float*)d_out;

    int N = in_sizes[0] / F;
    int E = in_sizes[1] / 2;
    const int* esrc = ei;
    const int* edst = ei + E;

    int nbkt = (N + BN - 1) / BN;

    char* w = (char*)d_ws;
    auto alloc = [&](size_t bytes) {
        char* p = w;
        w += (bytes + 255) & ~(size_t)255;
        return p;
    };
    int*   gfill   = (int*)alloc((size_t)MAXB * 4);
    int2*  offs2   = (int2*)alloc((size_t)N * 8);
    float* dinv    = (float*)alloc((size_t)N * 4);
    unsigned int* pairs = (unsigned int*)alloc((size_t)nbkt * CAP * 4);
    int*   csr     = (int*)alloc((size_t)nbkt * CAP * 4);
    unsigned short* hn2 = (unsigned short*)alloc((size_t)N * F * 2);
    unsigned short* wt1 = (unsigned short*)alloc((size_t)F * WSTRIDE * 2);
    unsigned short* wt2 = (unsigned short*)alloc((size_t)F * WSTRIDE * 2);
    // layer-1 hn (bf16, 25.6MB) lives in d_out (51.2MB fp32 buffer); it is
    // dead once the fused kernel finishes, and agg2 overwrites d_out last.
    unsigned short* hn1 = (unsigned short*)d_out;

    hipMemsetAsync(gfill, 0, (size_t)MAXB * 4, stream);

    int nbe = (E + EPB - 1) / EPB;
    bucket_scatter_kernel<<<nbe, 256, 0, stream>>>(esrc, edst, E, gfill, pairs);
    bucket_build_kernel<<<nbkt, 512, 0, stream>>>(pairs, gfill, N, offs2, dinv, csr);
    wt_prep_kernel<<<16, 256, 0, stream>>>(W1, W2, wt1, wt2);

    // layer 1 GEMM: x -> hn1 (in d_out)
    gemm_mfma_kernel<<<(N + 127) / 128, 256, 0, stream>>>(x, wt1, dinv, hn1, N);
    // fused agg1 + gemm2: hn1 -> hn2 (ws)
    fused_agg_gemm_kernel<<<(N + 63) / 64, 256, 0, stream>>>(
        hn1, csr, offs2, dinv, b1, wt2, hn2, N);
    // layer 2 aggregate: hn2 -> out (fp32, overwrites hn1 region of d_out)
    aggregate_kernel<<<(N + 7) / 8, 256, 0, stream>>>(
        hn2, csr, offs2, dinv, b2, out, N);
}

// Round 12
// 210.666 us; speedup vs baseline: 1.2127x; 1.0662x over previous
//
#include <hip/hip_runtime.h>
#include <hip/hip_bf16.h>

// ---------------------------------------------------------------------------
// 2-layer GCN:  x1 = relu(Agg(x @ W1) + b1);  out = relu(Agg(x1 @ W2) + b2)
// Agg: out[d] = dinv[d] * ( sum_{e: dst=d} hn[src_e] + hn[d] ),
//      hn[i] = (x@W)[i] * dinv[i]  (bf16),  dinv = rsqrt(deg+1).
// GEMM via v_mfma_f32_16x16x32_bf16 (fp32 accumulate), W pre-transposed bf16.
// CSR: fixed-stride 512-node buckets, bucket-local LDS randomness only.
// Aggregate (r7 config, converged): 16B/lane row gathers, 4 chains/16-lane
// group, csr prefetch. This round = r7 + wt_prep folded into scatter grid.
// ---------------------------------------------------------------------------

#define F 128
#define BN 512
#define LOG_BN 9
#define MAXB 512
#define EPB 4096
#define CAP 10240          // edges per bucket region (fixed stride)
#define WSTRIDE 136        // padded u16 stride (2-way max LDS bank aliasing)

typedef __attribute__((ext_vector_type(8))) short bh8;
typedef __attribute__((ext_vector_type(4))) float f32x4;

__device__ __forceinline__ unsigned short f2bf(float f) {
    __hip_bfloat16 h = __float2bfloat16(f);
    return *reinterpret_cast<unsigned short*>(&h);
}

__device__ __forceinline__ void acc8(float* a, uint4 q) {
    a[0] += __uint_as_float(q.x << 16);
    a[1] += __uint_as_float(q.x & 0xFFFF0000u);
    a[2] += __uint_as_float(q.y << 16);
    a[3] += __uint_as_float(q.y & 0xFFFF0000u);
    a[4] += __uint_as_float(q.z << 16);
    a[5] += __uint_as_float(q.z & 0xFFFF0000u);
    a[6] += __uint_as_float(q.w << 16);
    a[7] += __uint_as_float(q.w & 0xFFFF0000u);
}

// ---------------- CSR scatter + (appended blocks) wt prep ------------------
// blocks [0, nbe): scatter packed (dlocal<<20 | src) into bucket regions.
// blocks [nbe, nbe+16): transpose W1,W2 to bf16 padded [128][WSTRIDE] images.
__global__ __launch_bounds__(256) void scatter_and_wtprep_kernel(
    const int* __restrict__ src, const int* __restrict__ dst, int E, int nbe,
    int* __restrict__ gfill, unsigned int* __restrict__ pairs,
    const float* __restrict__ W1, const float* __restrict__ W2,
    unsigned short* __restrict__ wt1, unsigned short* __restrict__ wt2) {
    int t = threadIdx.x;
    if (blockIdx.x >= nbe) {                // ---- wt_prep section ----
        int gid = (blockIdx.x - nbe) * 256 + t;   // 0..4095
        const float* W = (gid < 2048) ? W1 : W2;
        unsigned short* wt = (gid < 2048) ? wt1 : wt2;
        int g = gid & 2047;
        int n = g >> 4;
        int kc = (g & 15) * 8;
        unsigned short u[8];
#pragma unroll
        for (int j = 0; j < 8; ++j) u[j] = f2bf(W[(size_t)(kc + j) * F + n]);
        uint4 v;
        v.x = (unsigned)u[0] | ((unsigned)u[1] << 16);
        v.y = (unsigned)u[2] | ((unsigned)u[3] << 16);
        v.z = (unsigned)u[4] | ((unsigned)u[5] << 16);
        v.w = (unsigned)u[6] | ((unsigned)u[7] << 16);
        *(uint4*)&wt[(size_t)n * WSTRIDE + kc] = v;
        return;
    }
    // ---- scatter section ----
    __shared__ int cnt[MAXB];
    __shared__ int base_l[MAXB];
    for (int k = t; k < MAXB; k += 256) cnt[k] = 0;
    __syncthreads();
    int base = blockIdx.x * EPB;
    int d[16], r[16];
#pragma unroll
    for (int j = 0; j < 16; ++j) {
        int e = base + j * 256 + t;
        d[j] = -1; r[j] = 0;
        if (e < E) {
            d[j] = dst[e];
            r[j] = atomicAdd(&cnt[d[j] >> LOG_BN], 1);
        }
    }
    __syncthreads();
    for (int k = t; k < MAXB; k += 256)
        base_l[k] = cnt[k] ? atomicAdd(&gfill[k], cnt[k]) : 0;
    __syncthreads();
#pragma unroll
    for (int j = 0; j < 16; ++j) {
        int e = base + j * 256 + t;
        if (e < E) {
            int b = d[j] >> LOG_BN;
            int pos = base_l[b] + r[j];
            if (pos < CAP) {
                unsigned int w = (unsigned int)src[e] |
                                 ((unsigned int)(d[j] & (BN - 1)) << 20);
                pairs[(size_t)b * CAP + pos] = w;
            }
        }
    }
}

// per-bucket: LDS-stage pairs, degree count, scan -> offs2/dinv, csr scatter
__global__ __launch_bounds__(512) void bucket_build_kernel(
    const unsigned int* __restrict__ pairs, const int* __restrict__ gfill,
    int N, int2* __restrict__ offs2, float* __restrict__ dinv,
    int* __restrict__ csr) {
    __shared__ unsigned int spair[CAP];
    __shared__ int deg[BN];
    __shared__ int fill[BN];
    __shared__ int sc[BN];
    int b = blockIdx.x, t = threadIdx.x;
    int node0 = b << LOG_BN;
    int nN = min(BN, N - node0);
    int lo = b * CAP;
    int cnt = min(gfill[b], CAP);
    deg[t] = 0; fill[t] = 0;
    for (int i = t; i < cnt; i += 512) spair[i] = pairs[(size_t)lo + i];
    __syncthreads();
    for (int i = t; i < cnt; i += 512)
        atomicAdd(&deg[(spair[i] >> 20) & (BN - 1)], 1);
    __syncthreads();
    int v = deg[t];
    sc[t] = v;
    __syncthreads();
    for (int off = 1; off < BN; off <<= 1) {
        int x = (t >= off) ? sc[t - off] : 0;
        __syncthreads();
        sc[t] += x;
        __syncthreads();
    }
    int ex = sc[t] - v;
    if (t < nN) {
        int beg = lo + ex;
        offs2[node0 + t] = make_int2(beg, beg + v);
        dinv[node0 + t] = rsqrtf((float)v + 1.0f);
    }
    __syncthreads();
    sc[t] = ex;
    __syncthreads();
    for (int i = t; i < cnt; i += 512) {
        unsigned int w = spair[i];
        int dl = (w >> 20) & (BN - 1);
        int rr = atomicAdd(&fill[dl], 1);
        csr[lo + sc[dl] + rr] = (int)(w & 0xFFFFFu);
    }
}

// --------------------------- MFMA GEMM ------------------------------------
// 128 rows per block (2 row-tiles of 64; W staged once); 4 waves. r7-proven.
template <bool A_BF16>
__global__ __launch_bounds__(256) void gemm_mfma_kernel(
    const void* __restrict__ Ain, const unsigned short* __restrict__ wt,
    const float* __restrict__ dinv, unsigned short* __restrict__ hn, int N) {
    __shared__ unsigned short sA[64 * WSTRIDE];
    __shared__ unsigned short sW[128 * WSTRIDE];
    int t = threadIdx.x;

    {   // stage Wt once per block (linear uint4 image copy)
        const uint4* ws = (const uint4*)wt;
        uint4* wd = (uint4*)sW;
#pragma unroll
        for (int j = 0; j < 9; ++j) {
            int i = j * 256 + t;
            if (i < 128 * WSTRIDE / 8) wd[i] = ws[i];
        }
    }

    int wid = t >> 6, lane = t & 63;
    int lr = lane & 15, lk = lane >> 4;

#pragma unroll
    for (int rt = 0; rt < 2; ++rt) {
        int row0 = blockIdx.x * 128 + rt * 64;
        if (row0 >= N) break;               // block-uniform

        if (A_BF16) {
            const unsigned short* A = (const unsigned short*)Ain;
#pragma unroll
            for (int j = 0; j < 4; ++j) {
                int i = j * 256 + t;
                int r = i >> 4, c8 = i & 15;
                int grow = row0 + r;
                uint4 v = make_uint4(0, 0, 0, 0);
                if (grow < N) v = *(const uint4*)(A + (size_t)grow * F + c8 * 8);
                *(uint4*)&sA[r * WSTRIDE + c8 * 8] = v;
            }
        } else {
            const float* A = (const float*)Ain;
#pragma unroll
            for (int j = 0; j < 8; ++j) {
                int i = j * 256 + t;
                int r = i >> 5, c4 = i & 31;
                int grow = row0 + r;
                float4 v = make_float4(0.f, 0.f, 0.f, 0.f);
                if (grow < N) v = *(const float4*)(A + (size_t)grow * F + c4 * 4);
                unsigned int p0 = (unsigned)f2bf(v.x) | ((unsigned)f2bf(v.y) << 16);
                unsigned int p1 = (unsigned)f2bf(v.z) | ((unsigned)f2bf(v.w) << 16);
                *(uint2*)&sA[r * WSTRIDE + c4 * 4] = make_uint2(p0, p1);
            }
        }
        __syncthreads();

        bh8 af[4];
        const unsigned short* aP = &sA[(wid * 16 + lr) * WSTRIDE + lk * 8];
#pragma unroll
        for (int ks = 0; ks < 4; ++ks) af[ks] = *(const bh8*)(aP + ks * 32);

        f32x4 acc[8];
#pragma unroll
        for (int c = 0; c < 8; ++c) acc[c] = (f32x4){0.f, 0.f, 0.f, 0.f};

        const unsigned short* bP = &sW[lr * WSTRIDE + lk * 8];
#pragma unroll
        for (int ct = 0; ct < 8; ++ct) {
            const unsigned short* bq = bP + ct * 16 * WSTRIDE;
            bh8 b0 = *(const bh8*)(bq);
            bh8 b1 = *(const bh8*)(bq + 32);
            bh8 b2 = *(const bh8*)(bq + 64);
            bh8 b3 = *(const bh8*)(bq + 96);
            acc[ct] = __builtin_amdgcn_mfma_f32_16x16x32_bf16(af[0], b0, acc[ct], 0, 0, 0);
            acc[ct] = __builtin_amdgcn_mfma_f32_16x16x32_bf16(af[1], b1, acc[ct], 0, 0, 0);
            acc[ct] = __builtin_amdgcn_mfma_f32_16x16x32_bf16(af[2], b2, acc[ct], 0, 0, 0);
            acc[ct] = __builtin_amdgcn_mfma_f32_16x16x32_bf16(af[3], b3, acc[ct], 0, 0, 0);
        }
        __syncthreads();

        float dv[4];
        int rbase = wid * 16 + lk * 4;
#pragma unroll
        for (int j = 0; j < 4; ++j) {
            int grow = row0 + rbase + j;
            dv[j] = (grow < N) ? dinv[grow] : 0.f;
        }
#pragma unroll
        for (int ct = 0; ct < 8; ++ct) {
#pragma unroll
            for (int j = 0; j < 4; ++j)
                sA[(rbase + j) * WSTRIDE + ct * 16 + lr] = f2bf(acc[ct][j] * dv[j]);
        }
        __syncthreads();
#pragma unroll
        for (int j = 0; j < 4; ++j) {
            int i = j * 256 + t;
            int r = i >> 4, c8 = i & 15;
            int grow = row0 + r;
            if (grow < N)
                *(uint4*)(hn + (size_t)grow * F + c8 * 8) =
                    *(const uint4*)&sA[r * WSTRIDE + c8 * 8];
        }
        __syncthreads();
    }
}

// --------------------------- aggregation ----------------------------------
// 32 lanes per node: eo = lane>>4 (edge parity), cg = lane&15 (16B column
// group). Four gather chains in flight per 16-lane group; csr prefetched.
template <bool OUT_BF16>
__global__ __launch_bounds__(256) void aggregate_kernel(
    const unsigned short* __restrict__ hn, const int* __restrict__ csr,
    const int2* __restrict__ offs2, const float* __restrict__ dinv,
    const float* __restrict__ bias, void* __restrict__ outv, int N) {
    int node = blockIdx.x * 8 + (threadIdx.x >> 5);
    if (node >= N) return;
    int half = threadIdx.x & 31;
    int eo = half >> 4;
    int cg = half & 15;

    const uint4* hn4 = (const uint4*)hn;   // 16 uint4 per 256B row
    float a0[8], a1[8], a2[8], a3[8];
#pragma unroll
    for (int j = 0; j < 8; ++j) { a0[j] = 0.f; a1[j] = 0.f; a2[j] = 0.f; a3[j] = 0.f; }
    if (eo == 0) {                          // self-loop on parity-0 group
        uint4 q = hn4[(size_t)node * 16 + cg];
        acc8(a0, q);
    }

    int2 oo = offs2[node];
    int e0 = oo.x + eo;                     // group's edges: e0, e0+2, ...
    int d = oo.y - e0;
    int cnt = (d <= 0) ? 0 : ((d + 1) >> 1);

    int i0 = (0 < cnt) ? csr[e0]     : -1;
    int i1 = (1 < cnt) ? csr[e0 + 2] : -1;
    int i2 = (2 < cnt) ? csr[e0 + 4] : -1;
    int i3 = (3 < cnt) ? csr[e0 + 6] : -1;
    int k = 0;
    while (k < cnt) {
        uint4 q0 = make_uint4(0,0,0,0), q1 = q0, q2 = q0, q3 = q0;
        if (i0 >= 0) q0 = hn4[(size_t)i0 * 16 + cg];
        if (i1 >= 0) q1 = hn4[(size_t)i1 * 16 + cg];
        if (i2 >= 0) q2 = hn4[(size_t)i2 * 16 + cg];
        if (i3 >= 0) q3 = hn4[(size_t)i3 * 16 + cg];
        int kn = k + 4;
        i0 = (kn     < cnt) ? csr[e0 + 2 * kn]     : -1;   // prefetch next
        i1 = (kn + 1 < cnt) ? csr[e0 + 2 * kn + 2] : -1;
        i2 = (kn + 2 < cnt) ? csr[e0 + 2 * kn + 4] : -1;
        i3 = (kn + 3 < cnt) ? csr[e0 + 2 * kn + 6] : -1;
        acc8(a0, q0);
        acc8(a1, q1);
        acc8(a2, q2);
        acc8(a3, q3);
        k = kn;
    }

#pragma unroll
    for (int j = 0; j < 8; ++j) {
        a0[j] += a1[j];
        a2[j] += a3[j];
        a0[j] += a2[j];
        a0[j] += __shfl_xor(a0[j], 16, 32);
    }

    if (eo == 0) {
        float sc = dinv[node];
        float4 b0 = ((const float4*)bias)[cg * 2];
        float4 b1 = ((const float4*)bias)[cg * 2 + 1];
        float o[8];
        o[0] = fmaxf(fmaf(a0[0], sc, b0.x), 0.f);
        o[1] = fmaxf(fmaf(a0[1], sc, b0.y), 0.f);
        o[2] = fmaxf(fmaf(a0[2], sc, b0.z), 0.f);
        o[3] = fmaxf(fmaf(a0[3], sc, b0.w), 0.f);
        o[4] = fmaxf(fmaf(a0[4], sc, b1.x), 0.f);
        o[5] = fmaxf(fmaf(a0[5], sc, b1.y), 0.f);
        o[6] = fmaxf(fmaf(a0[6], sc, b1.z), 0.f);
        o[7] = fmaxf(fmaf(a0[7], sc, b1.w), 0.f);
        if (OUT_BF16) {
            uint4 p;
            p.x = (unsigned)f2bf(o[0]) | ((unsigned)f2bf(o[1]) << 16);
            p.y = (unsigned)f2bf(o[2]) | ((unsigned)f2bf(o[3]) << 16);
            p.z = (unsigned)f2bf(o[4]) | ((unsigned)f2bf(o[5]) << 16);
            p.w = (unsigned)f2bf(o[6]) | ((unsigned)f2bf(o[7]) << 16);
            ((uint4*)outv)[(size_t)node * 16 + cg] = p;
        } else {
            float4* op = (float4*)((float*)outv + (size_t)node * F + cg * 8);
            op[0] = make_float4(o[0], o[1], o[2], o[3]);
            op[1] = make_float4(o[4], o[5], o[6], o[7]);
        }
    }
}

extern "C" void kernel_launch(void* const* d_in, const int* in_sizes, int n_in,
                              void* d_out, int out_size, void* d_ws, size_t ws_size,
                              hipStream_t stream) {
    const float* x   = (const float*)d_in[0];
    const int*   ei  = (const int*)d_in[1];   // int64 in reference -> int32 here
    const float* W1  = (const float*)d_in[2];
    const float* b1  = (const float*)d_in[3];
    const float* W2  = (const float*)d_in[4];
    const float* b2  = (const float*)d_in[5];
    float* out       = (float*)d_out;

    int N = in_sizes[0] / F;
    int E = in_sizes[1] / 2;
    const int* esrc = ei;
    const int* edst = ei + E;

    int nbkt = (N + BN - 1) / BN;

    char* w = (char*)d_ws;
    auto alloc = [&](size_t bytes) {
        char* p = w;
        w += (bytes + 255) & ~(size_t)255;
        return p;
    };
    int*   gfill   = (int*)alloc((size_t)MAXB * 4);
    int2*  offs2   = (int2*)alloc((size_t)N * 8);
    float* dinv    = (float*)alloc((size_t)N * 4);
    unsigned int* pairs = (unsigned int*)alloc((size_t)nbkt * CAP * 4);
    int*   csr     = (int*)alloc((size_t)nbkt * CAP * 4);
    unsigned short* hn  = (unsigned short*)alloc((size_t)N * F * 2);
    unsigned short* wt1 = (unsigned short*)alloc((size_t)F * WSTRIDE * 2);
    unsigned short* wt2 = (unsigned short*)alloc((size_t)F * WSTRIDE * 2);
    // layer-1 bf16 activations live in spare d_out space (51.2MB f32 buffer,
    // x1b needs 25.6MB; layer-2 aggregate fully overwrites d_out afterwards)
    unsigned short* x1b = (unsigned short*)d_out;

    hipMemsetAsync(gfill, 0, (size_t)MAXB * 4, stream);

    int nbe = (E + EPB - 1) / EPB;
    scatter_and_wtprep_kernel<<<nbe + 16, 256, 0, stream>>>(
        esrc, edst, E, nbe, gfill, pairs, W1, W2, wt1, wt2);
    bucket_build_kernel<<<nbkt, 512, 0, stream>>>(pairs, gfill, N, offs2, dinv, csr);

    int gblocks = (N + 127) / 128;
    int ablocks = (N + 7) / 8;

    // layer 1
    gemm_mfma_kernel<false><<<gblocks, 256, 0, stream>>>(x, wt1, dinv, hn, N);
    aggregate_kernel<true><<<ablocks, 256, 0, stream>>>(hn, csr, offs2, dinv, b1, x1b, N);
    // layer 2
    gemm_mfma_kernel<true><<<gblocks, 256, 0, stream>>>(x1b, wt2, dinv, hn, N);
    aggregate_kernel<false><<<ablocks, 256, 0, stream>>>(hn, csr, offs2, dinv, b2, out, N);
}